// Round 18
// baseline (887.225 us; speedup 1.0000x reference)
//
#include <hip/hip_runtime.h>

typedef __bf16 bf16x8 __attribute__((ext_vector_type(8)));
typedef float f32x4 __attribute__((ext_vector_type(4)));
typedef unsigned short ushortT;

__device__ __forceinline__ unsigned short f2bf(float f) {
    unsigned u = __float_as_uint(f);
    u += 0x7fffu + ((u >> 16) & 1u);
    return (unsigned short)(u >> 16);
}
__device__ __forceinline__ float bf2f(unsigned short h) {
    return __uint_as_float((unsigned)h << 16);
}

// ---------------- prep0: xpad + conv1 weights + A-tile-packed residual weight prep ---------
// (validated r17: write-side already ideal; ci-phased 27.8KB LDS, contiguous 512B tap runs)
__global__ __launch_bounds__(256) void prep0(const float* __restrict__ x,
                                             const float* __restrict__ c1w,
                                             const float* __restrict__ w11, const float* __restrict__ w12,
                                             const float* __restrict__ w21, const float* __restrict__ w22,
                                             const float* __restrict__ w31, const float* __restrict__ w32,
                                             const float* __restrict__ w41, const float* __restrict__ w42,
                                             ushortT* __restrict__ xp,
                                             ushortT* __restrict__ o1,
                                             ushortT* __restrict__ o11, ushortT* __restrict__ o12,
                                             ushortT* __restrict__ o21, ushortT* __restrict__ o22,
                                             ushortT* __restrict__ o31, ushortT* __restrict__ o32,
                                             ushortT* __restrict__ o41, ushortT* __restrict__ o42) {
    __shared__ float tile[6960]; // 16 x 435 f32 = 27,840 B
    int bid = blockIdx.x, tid = threadIdx.x;
    if (bid < 1737) {
        long idx = (long)bid * 256 + tid;
        if (idx >= 444528L) return;
        int q = (int)(idx % 6); long r = idx / 6;
        int h = (int)(r % 42); r /= 42;
        int d = (int)(r % 42); int t = (int)(r / 42);
        int tt = t - 3, dd = d - 3, hh = h - 3;
        bool rok = ((unsigned)tt < 36u) && ((unsigned)dd < 36u) && ((unsigned)hh < 36u);
        const float* src = x + (((long)tt * 36 + dd) * 36 + hh) * 36;
        union { ushortT s[8]; uint4 u; } v;
#pragma unroll
        for (int j = 0; j < 8; ++j) {
            int ww = q * 8 + j - 3;
            float f = (rok && (unsigned)ww < 36u) ? src[ww] : 0.f;
            v.s[j] = f2bf(f);
        }
        *(uint4*)(xp + idx * 8) = v.u;
        return;
    }
    if (bid < 2521) {
        int e = (bid - 1737) * 256 + tid;
        if (e < 200704) {
            int k = e % 3136, co = e / 3136;
            int kw = k & 7, kh = (k >> 3) & 7, kdt = k >> 6;
            int kt = kdt / 7, kd = kdt % 7;
            float v = 0.f;
            if (kh < 7 && kw < 7)
                v = c1w[(size_t)(kt * 64 + co) * 343 + kd * 49 + kh * 7 + kw];
            o1[e] = f2bf(v);
        }
        return;
    }

    int wb = bid - 2521; // < 3072
    const float* in; ushortT* out; int Ci, Co;
    int base;
    if (wb < 192) {
        if (wb < 48) {
            if (wb < 24) { in = w11; out = o11; Ci = 64; Co = 64; base = 0; }
            else         { in = w12; out = o12; Ci = 64; Co = 64; base = 24; }
        } else if (wb < 96) { in = w21; out = o21; Ci = 64;  Co = 128; base = 48; }
        else                { in = w22; out = o22; Ci = 128; Co = 128; base = 96; }
    } else if (wb < 768) {
        if (wb < 384) { in = w31; out = o31; Ci = 128; Co = 256; base = 192; }
        else          { in = w32; out = o32; Ci = 256; Co = 256; base = 384; }
    } else {
        if (wb < 1536) { in = w41; out = o41; Ci = 256; Co = 512; base = 768; }
        else           { in = w42; out = o42; Ci = 512; Co = 512; base = 1536; }
    }
    int lb = wb - base;
    int nCb = Co >> 4, nKb = Ci >> 5;
    int per_i = nCb * nKb;
    int i = lb / per_i;
    int r2 = lb - i * per_i;
    int cb = r2 / nKb, kb = r2 - cb * nKb;

    size_t costride = (size_t)Ci * 27;
    ushortT* dst0 = out + (((size_t)(i * 27) * nCb + cb) * nKb + kb) * 512;
    size_t tapstride = (size_t)nCb * nKb * 512;

    for (int ph = 0; ph < 2; ++ph) {
        const float* src0 = in + ((size_t)(i * Co + cb * 16) * Ci + kb * 32 + ph * 16) * 27;
        for (int e = tid; e < 1728; e += 256) {
            int cl = e / 108, q = e - cl * 108;
            *(float4*)(tile + cl * 435 + 4 * q) = *(const float4*)(src0 + cl * costride + 4 * q);
        }
        __syncthreads();
        for (int e = tid; e < 864; e += 256) {
            int tap = e >> 5, wl = e & 31;
            int gh = wl >> 4, l15 = wl & 15;
            union { ushortT s[8]; uint4 u; } v;
#pragma unroll
            for (int j = 0; j < 8; ++j)
                v.s[j] = f2bf(tile[l15 * 435 + (gh * 8 + j) * 27 + tap]);
            *(uint4*)(dst0 + (size_t)tap * tapstride + (ph * 32 + wl) * 8) = v.u;
        }
        __syncthreads();
    }
}

// ---------------- mega: conv1 MFMA, stride-26 LDS + bijective XCD swizzle (validated r17) --
__global__ __launch_bounds__(128) void mega_kernel(
        const ushortT* __restrict__ xp, const ushortT* __restrict__ aw,
        ushortT* __restrict__ outc1) {
    __shared__ __align__(16) ushortT smem[12376]; // 2 x (238 rows x 26)
    int bid = blockIdx.x, tid = threadIdx.x;

    {
        int xcd = bid & 7, loc = bid >> 3;
        bid = (xcd < 6) ? (xcd * 169 + loc) : (1014 + (xcd - 6) * 168 + loc);
    }

    int wt = bid % 5; int r = bid / 5;
    int ht = r % 5; r /= 5;
    int dt = r % 3; int ot = r / 3;
    int ow0 = wt * 4, oh0 = ht * 4, od0 = dt * 6;
    int gw0 = 2 * ow0, gh0 = 2 * oh0, gd0 = 2 * od0;

    int lane = tid & 63, wv = tid >> 6;
    int l15 = lane & 15, g = lane >> 4;
    int dh = l15 >> 2, dw = l15 & 3;

    const ushortT* ap0 = aw + (size_t)(wv * 32 + l15) * 3136 + g * 8;
    const ushortT* ap1 = ap0 + 16 * 3136;

    ushortT* curb = smem;
    ushortT* nxtb = smem + 6188;

    auto stage = [&](ushortT* buf, int kt) {
        int gt = 2 * ot + kt;
        for (int rr = tid; rr < 238; rr += 128) {
            int ld = rr / 14, lh = rr - ld * 14;
            const ushortT* s = xp +
                ((size_t)((gt * 42 + gd0 + ld) * 42 + gh0 + lh)) * 48 + gw0;
            uint4 a = *(const uint4*)s;
            uint4 b = *(const uint4*)(s + 8);
            unsigned* d = (unsigned*)buf + rr * 13;
            d[0] = a.x; d[1] = a.y; d[2] = a.z; d[3] = a.w;
            d[4] = b.x; d[5] = b.y; d[6] = b.z; d[7] = b.w;
        }
    };

    f32x4 acc[2][6];
#pragma unroll
    for (int c = 0; c < 2; ++c)
#pragma unroll
        for (int m = 0; m < 6; ++m) acc[c][m] = (f32x4){0.f, 0.f, 0.f, 0.f};

    stage(curb, 0);
    __syncthreads();

    int lhl = (2 * dh + g) * 26 + 2 * dw;
    int kidx = 0;
    for (int kt = 0; kt < 7; ++kt) {
        if (kt < 6) stage(nxtb, kt + 1);
        for (int kd = 0; kd < 7; ++kd) {
            int C0 = kd * 364 + lhl;
#pragma unroll
            for (int khq = 0; khq < 2; ++khq) {
                bf16x8 a0 = *(const bf16x8*)(ap0 + kidx);
                bf16x8 a1 = *(const bf16x8*)(ap1 + kidx);
                kidx += 32;
                int C = C0 + khq * 104;
#pragma unroll
                for (int m = 0; m < 6; ++m) {
                    int off = C + m * 728;
                    union { unsigned u[4]; bf16x8 v; } bb;
                    bb.u[0] = *(const unsigned*)(curb + off);
                    bb.u[1] = *(const unsigned*)(curb + off + 2);
                    bb.u[2] = *(const unsigned*)(curb + off + 4);
                    bb.u[3] = *(const unsigned*)(curb + off + 6);
                    acc[0][m] = __builtin_amdgcn_mfma_f32_16x16x32_bf16(a0, bb.v, acc[0][m], 0, 0, 0);
                    acc[1][m] = __builtin_amdgcn_mfma_f32_16x16x32_bf16(a1, bb.v, acc[1][m], 0, 0, 0);
                }
            }
        }
        __syncthreads();
        ushortT* t2 = curb; curb = nxtb; nxtb = t2;
    }

    int oh = oh0 + dh, ow = ow0 + dw;
    if (oh < 18 && ow < 18) {
#pragma unroll
        for (int m = 0; m < 6; ++m) {
            int od = od0 + m;
            int pos = ((ot * 18 + od) * 18 + oh) * 18 + ow;
#pragma unroll
            for (int c = 0; c < 2; ++c) {
                ushort4 st;
                st.x = f2bf(fmaxf(acc[c][m][0], 0.f));
                st.y = f2bf(fmaxf(acc[c][m][1], 0.f));
                st.z = f2bf(fmaxf(acc[c][m][2], 0.f));
                st.w = f2bf(fmaxf(acc[c][m][3], 0.f));
                *(ushort4*)(outc1 + (size_t)pos * 64 + wv * 32 + c * 16 + g * 4) = st;
            }
        }
    }
}

// ---------------- maxpool 3^4 s2 p1: bf16 [18^4][64] -> bf16 [9^4][64]; zero-fills zb ------
__global__ void maxpool2(const ushortT* __restrict__ in, ushortT* __restrict__ out,
                         ushortT* __restrict__ zb) {
    int idx = blockIdx.x * 256 + threadIdx.x;
    if (idx < 128) zb[idx] = 0;
    if (idx >= 6561 * 16) return;
    int c4 = idx & 15;
    int p = idx >> 4;
    int ow = p % 9; int t = p / 9;
    int oh = t % 9; t /= 9;
    int od = t % 9; int ot = t / 9;
    ushort4 m = {0, 0, 0, 0};
    for (int kt = 0; kt < 3; ++kt) { int it = 2 * ot + kt - 1; if ((unsigned)it >= 18u) continue;
        for (int kd = 0; kd < 3; ++kd) { int id = 2 * od + kd - 1; if ((unsigned)id >= 18u) continue;
            for (int kh = 0; kh < 3; ++kh) { int ih = 2 * oh + kh - 1; if ((unsigned)ih >= 18u) continue;
                int rb = ((it * 18 + id) * 18 + ih) * 18;
                for (int kw = 0; kw < 3; ++kw) { int iw = 2 * ow + kw - 1; if ((unsigned)iw >= 18u) continue;
                    ushort4 v = *(const ushort4*)(in + (size_t)(rb + iw) * 64 + c4 * 4);
                    m.x = v.x > m.x ? v.x : m.x;
                    m.y = v.y > m.y ? v.y : m.y;
                    m.z = v.z > m.z ? v.z : m.z;
                    m.w = v.w > m.w ? v.w : m.w;
                }
            }
        }
    }
    *(ushort4*)(out + (size_t)p * 64 + c4 * 4) = m;
}

// ---------------- MFMA implicit-GEMM residual conv, packed A-tiles, FUSED epilogue --------
// Unsplit K (KC = Ci/32 per block). Runtime (i,kd,kh) loops; kw/kc unrolled so the rotating
// accumulator index (kw*KC+kc)&3 stays compile-time (rule #20). Optional merged 1x1 dw.
template <int KC>
__global__ void convmfma(const ushortT* __restrict__ xb, const ushortT* __restrict__ wt,
                         const float* __restrict__ bias, const ushortT* __restrict__ res,
                         ushortT* __restrict__ outb, const ushortT* __restrict__ zq,
                         int Ci, int Co, int T, int O, int stride,
                         const float* __restrict__ dwW, ushortT* __restrict__ dwOut) {
    if (dwW && blockIdx.y == (unsigned)(Co >> 6)) {
        int O2 = O * O, O3 = O2 * O, O4 = O3 * O;
        int total = Co * O4;
        int sthr = gridDim.x * gridDim.z * 256;
        for (int idx = (blockIdx.z * gridDim.x + blockIdx.x) * 256 + threadIdx.x;
             idx < total; idx += sthr) {
            int co = idx % Co;
            int pos = idx / Co;
            int ow = pos % O, oh = (pos / O) % O, od = (pos / O2) % O, ot = pos / O3;
            int ip = (((2 * ot) * T + 2 * od) * T + 2 * oh) * T + 2 * ow;
            const ushortT* xpp = xb + (size_t)ip * Ci;
            const float* wp = dwW + (size_t)co * Ci;
            float acc = 0.f;
            for (int c8 = 0; c8 < Ci; c8 += 8) {
                uint4 xv = *(const uint4*)(xpp + c8);
                float4 w0 = *(const float4*)(wp + c8);
                float4 w1 = *(const float4*)(wp + c8 + 4);
                acc = fmaf(bf2f((unsigned short)(xv.x & 0xffff)), w0.x, acc);
                acc = fmaf(bf2f((unsigned short)(xv.x >> 16)),    w0.y, acc);
                acc = fmaf(bf2f((unsigned short)(xv.y & 0xffff)), w0.z, acc);
                acc = fmaf(bf2f((unsigned short)(xv.y >> 16)),    w0.w, acc);
                acc = fmaf(bf2f((unsigned short)(xv.z & 0xffff)), w1.x, acc);
                acc = fmaf(bf2f((unsigned short)(xv.z >> 16)),    w1.y, acc);
                acc = fmaf(bf2f((unsigned short)(xv.w & 0xffff)), w1.z, acc);
                acc = fmaf(bf2f((unsigned short)(xv.w >> 16)),    w1.w, acc);
            }
            dwOut[idx] = f2bf(acc);
        }
        return;
    }

    int lane = threadIdx.x & 63;
    int wv = threadIdx.x >> 6;
    int p0 = blockIdx.x * 16;
    int cb = blockIdx.y * 4 + wv;
    int co0 = cb * 16;
    size_t nCb = Co >> 4, nKb = Ci >> 5;

    int pn = p0 + (lane & 15);
    int O2 = O * O, O3 = O2 * O, O4 = O3 * O;
    bool pv = pn < O4;
    int pc = pv ? pn : 0;
    int ow = pc % O, oh = (pc / O) % O, od = (pc / O2) % O, ot = pc / O3;
    int g = lane >> 4;
    int kl = g * 8;

    const ushortT* zp = zq + g * 8;

    f32x4 acc[4];
#pragma unroll
    for (int a = 0; a < 4; ++a) acc[a] = (f32x4){0.f, 0.f, 0.f, 0.f};

    int itb = ot * stride - 1, idb = od * stride - 1, ihb = oh * stride - 1, iwb = ow * stride - 1;

    for (int i = 0; i < 3; ++i) {
        int it = itb + i;
        bool vt = pv && ((unsigned)it < (unsigned)T);
        for (int kd = 0; kd < 3; ++kd) {
            int id = idb + kd;
            bool vdd = vt && ((unsigned)id < (unsigned)T);
            int btd = (it * T + id) * T;
            for (int kh = 0; kh < 3; ++kh) {
                int ih = ihb + kh;
                bool vh = vdd && ((unsigned)ih < (unsigned)T);
                int tap0 = (i * 9 + kd * 3 + kh) * 3;
#pragma unroll
                for (int kw = 0; kw < 3; ++kw) {
                    int iw = iwb + kw;
                    bool v = vh && ((unsigned)iw < (unsigned)T);
                    int ip = (btd + ih) * T + iw;
                    const ushortT* bp = v ? (xb + (size_t)ip * Ci + kl) : zp;
                    const ushortT* ap = wt + (((size_t)(tap0 + kw) * nCb + cb) * nKb) * 512
                                        + lane * 8;
#pragma unroll
                    for (int kc = 0; kc < KC; ++kc) {
                        bf16x8 av = *(const bf16x8*)(ap + kc * 512);
                        bf16x8 bv = *(const bf16x8*)(bp + kc * 32);
                        acc[(kw * KC + kc) & 3] =
                            __builtin_amdgcn_mfma_f32_16x16x32_bf16(av, bv,
                                acc[(kw * KC + kc) & 3], 0, 0, 0);
                    }
                }
            }
        }
    }

    if (!pv) return;
    f32x4 asum;
#pragma unroll
    for (int r = 0; r < 4; ++r)
        asum[r] = (acc[0][r] + acc[1][r]) + (acc[2][r] + acc[3][r]);
    int cob = co0 + g * 4;
    float bb[4] = {0.f, 0.f, 0.f, 0.f};
    for (int i = 0; i < 3; ++i) {
        int it = itb + i;
        if ((unsigned)it < (unsigned)T) {
#pragma unroll
            for (int rr = 0; rr < 4; ++rr) bb[rr] += bias[i * Co + cob + rr];
        }
    }
    float rv[4] = {0.f, 0.f, 0.f, 0.f};
    if (res) {
        ushort4 r4 = *(const ushort4*)(res + (size_t)pn * Co + cob);
        rv[0] = bf2f(r4.x); rv[1] = bf2f(r4.y); rv[2] = bf2f(r4.z); rv[3] = bf2f(r4.w);
    }
    ushort4 st;
    st.x = f2bf(fmaxf(asum[0] + bb[0] + rv[0], 0.f));
    st.y = f2bf(fmaxf(asum[1] + bb[1] + rv[1], 0.f));
    st.z = f2bf(fmaxf(asum[2] + bb[2] + rv[2], 0.f));
    st.w = f2bf(fmaxf(asum[3] + bb[3] + rv[3], 0.f));
    *(ushort4*)(outb + (size_t)pn * Co + cob) = st;
}

// ---------------- avgpool 2^4 + FC (512 -> 1) ----------------
__global__ void avgfc2(const ushortT* __restrict__ xin, const float* __restrict__ fw,
                       const float* __restrict__ fb, float* __restrict__ out) {
    __shared__ float ls[8];
    int t = threadIdx.x; // 512
    float s = 0.f;
#pragma unroll
    for (int pp = 0; pp < 16; ++pp) s += bf2f(xin[pp * 512 + t]);
    s = s * (1.f / 16.f) * fw[t];
    for (int off = 32; off > 0; off >>= 1) s += __shfl_xor(s, off, 64);
    if ((t & 63) == 0) ls[t >> 6] = s;
    __syncthreads();
    if (t == 0) {
        float tot = 0.f;
#pragma unroll
        for (int i = 0; i < 8; ++i) tot += ls[i];
        out[0] = tot + fb[0];
    }
}

extern "C" void kernel_launch(void* const* d_in, const int* in_sizes, int n_in,
                              void* d_out, int out_size, void* d_ws, size_t ws_size,
                              hipStream_t stream) {
    const float* x       = (const float*)d_in[0];
    const float* conv1_w = (const float*)d_in[1];
    const float* l1_w1 = (const float*)d_in[2];
    const float* l1_b1 = (const float*)d_in[3];
    const float* l1_w2 = (const float*)d_in[4];
    const float* l1_b2 = (const float*)d_in[5];
    const float* l2_w1 = (const float*)d_in[6];
    const float* l2_b1 = (const float*)d_in[7];
    const float* l2_w2 = (const float*)d_in[8];
    const float* l2_b2 = (const float*)d_in[9];
    const float* l2_dw = (const float*)d_in[10];
    const float* l3_w1 = (const float*)d_in[11];
    const float* l3_b1 = (const float*)d_in[12];
    const float* l3_w2 = (const float*)d_in[13];
    const float* l3_b2 = (const float*)d_in[14];
    const float* l3_dw = (const float*)d_in[15];
    const float* l4_w1 = (const float*)d_in[16];
    const float* l4_b1 = (const float*)d_in[17];
    const float* l4_w2 = (const float*)d_in[18];
    const float* l4_b2 = (const float*)d_in[19];
    const float* l4_dw = (const float*)d_in[20];
    const float* fc_w  = (const float*)d_in[21];
    const float* fc_b  = (const float*)d_in[22];
    float* outp = (float*)d_out;

    char* bp = (char*)d_ws;
    auto alloc = [&](size_t bytes) {
        char* r = bp;
        bp += (bytes + 255) & ~(size_t)255;
        return (void*)r;
    };
    ushortT* A16 = (ushortT*)alloc(6718464ull * 2); // conv1 out bf16 [18^4][64]
    ushortT* XP  = (ushortT*)alloc(3556224ull * 2); // padded bf16 x [42][42][42][48]
    ushortT* Aw1 = (ushortT*)alloc(200704ull * 2);
    ushortT* X0 = (ushortT*)alloc(419904ull * 2);
    ushortT* Y1 = (ushortT*)alloc(419904ull * 2);
    ushortT* X1 = (ushortT*)alloc(419904ull * 2);
    ushortT* Y2 = (ushortT*)alloc(80000ull * 2);
    ushortT* R2 = (ushortT*)alloc(80000ull * 2);
    ushortT* X2 = (ushortT*)alloc(80000ull * 2);
    ushortT* Y3 = (ushortT*)alloc(20736ull * 2);
    ushortT* R3 = (ushortT*)alloc(20736ull * 2);
    ushortT* X3 = (ushortT*)alloc(20736ull * 2);
    ushortT* Y4 = (ushortT*)alloc(8192ull * 2);
    ushortT* R4 = (ushortT*)alloc(8192ull * 2);
    ushortT* X4 = (ushortT*)alloc(8192ull * 2);
    ushortT* W11 = (ushortT*)alloc(331776ull * 2);
    ushortT* W12 = (ushortT*)alloc(331776ull * 2);
    ushortT* W21 = (ushortT*)alloc(663552ull * 2);
    ushortT* W22 = (ushortT*)alloc(1327104ull * 2);
    ushortT* W31 = (ushortT*)alloc(2654208ull * 2);
    ushortT* W32 = (ushortT*)alloc(5308416ull * 2);
    ushortT* W41 = (ushortT*)alloc(10616832ull * 2);
    ushortT* W42 = (ushortT*)alloc(21233664ull * 2);
    ushortT* ZB = (ushortT*)alloc(256);
    if ((size_t)(bp - (char*)d_ws) > ws_size) return; // workspace too small: fail cleanly

    // 1) pad/convert x + conv1 weights + packed residual weight prep
    prep0<<<5593, 256, 0, stream>>>(x, conv1_w,
                                    l1_w1, l1_w2, l2_w1, l2_w2, l3_w1, l3_w2, l4_w1, l4_w2,
                                    XP, Aw1,
                                    W11, W12, W21, W22, W31, W32, W41, W42);

    // 2) conv1 MFMA (stride-26 LDS + XCD swizzle)
    mega_kernel<<<1350, 128, 0, stream>>>(XP, Aw1, A16);

    // 3) stem pool (+ zero ZB)
    maxpool2<<<411, 256, 0, stream>>>(A16, X0, ZB);

    // 4) layer1 (fused epilogue)
    convmfma<2><<<dim3(411, 1, 1), 256, 0, stream>>>(
        X0, W11, l1_b1, nullptr, Y1, ZB, 64, 64, 9, 9, 1, nullptr, nullptr);
    convmfma<2><<<dim3(411, 1, 1), 256, 0, stream>>>(
        Y1, W12, l1_b2, X0, X1, ZB, 64, 64, 9, 9, 1, nullptr, nullptr);

    // 5) layer2 (dw merged into c1)
    convmfma<2><<<dim3(40, 3, 1), 256, 0, stream>>>(
        X1, W21, l2_b1, nullptr, Y2, ZB, 64, 128, 9, 5, 2, l2_dw, R2);
    convmfma<4><<<dim3(40, 2, 1), 256, 0, stream>>>(
        Y2, W22, l2_b2, R2, X2, ZB, 128, 128, 5, 5, 1, nullptr, nullptr);

    // 6) layer3 (unsplit, fused; dw merged into c1)
    convmfma<4><<<dim3(6, 5, 1), 256, 0, stream>>>(
        X2, W31, l3_b1, nullptr, Y3, ZB, 128, 256, 5, 3, 2, l3_dw, R3);
    convmfma<8><<<dim3(6, 4, 1), 256, 0, stream>>>(
        Y3, W32, l3_b2, R3, X3, ZB, 256, 256, 3, 3, 1, nullptr, nullptr);

    // 7) layer4 (unsplit, fused; dw merged into c1; extra x-blocks feed dw threads)
    convmfma<8><<<dim3(4, 9, 1), 256, 0, stream>>>(
        X3, W41, l4_b1, nullptr, Y4, ZB, 256, 512, 3, 2, 2, l4_dw, R4);
    convmfma<16><<<dim3(1, 8, 1), 256, 0, stream>>>(
        Y4, W42, l4_b2, R4, X4, ZB, 512, 512, 2, 2, 1, nullptr, nullptr);

    // 8) head
    avgfc2<<<1, 512, 0, stream>>>(X4, fc_w, fc_b, outp);
}

// Round 19
// 535.216 us; speedup vs baseline: 1.6577x; 1.6577x over previous
//
#include <hip/hip_runtime.h>

typedef __bf16 bf16x8 __attribute__((ext_vector_type(8)));
typedef float f32x4 __attribute__((ext_vector_type(4)));
typedef unsigned short ushortT;

__device__ __forceinline__ unsigned short f2bf(float f) {
    unsigned u = __float_as_uint(f);
    u += 0x7fffu + ((u >> 16) & 1u);
    return (unsigned short)(u >> 16);
}
__device__ __forceinline__ float bf2f(unsigned short h) {
    return __uint_as_float((unsigned)h << 16);
}

// ---------------- prep0: xpad + conv1 weights + A-tile-packed residual weight prep ---------
// (validated r17)
__global__ __launch_bounds__(256) void prep0(const float* __restrict__ x,
                                             const float* __restrict__ c1w,
                                             const float* __restrict__ w11, const float* __restrict__ w12,
                                             const float* __restrict__ w21, const float* __restrict__ w22,
                                             const float* __restrict__ w31, const float* __restrict__ w32,
                                             const float* __restrict__ w41, const float* __restrict__ w42,
                                             ushortT* __restrict__ xp,
                                             ushortT* __restrict__ o1,
                                             ushortT* __restrict__ o11, ushortT* __restrict__ o12,
                                             ushortT* __restrict__ o21, ushortT* __restrict__ o22,
                                             ushortT* __restrict__ o31, ushortT* __restrict__ o32,
                                             ushortT* __restrict__ o41, ushortT* __restrict__ o42) {
    __shared__ float tile[6960]; // 16 x 435 f32 = 27,840 B
    int bid = blockIdx.x, tid = threadIdx.x;
    if (bid < 1737) {
        long idx = (long)bid * 256 + tid;
        if (idx >= 444528L) return;
        int q = (int)(idx % 6); long r = idx / 6;
        int h = (int)(r % 42); r /= 42;
        int d = (int)(r % 42); int t = (int)(r / 42);
        int tt = t - 3, dd = d - 3, hh = h - 3;
        bool rok = ((unsigned)tt < 36u) && ((unsigned)dd < 36u) && ((unsigned)hh < 36u);
        const float* src = x + (((long)tt * 36 + dd) * 36 + hh) * 36;
        union { ushortT s[8]; uint4 u; } v;
#pragma unroll
        for (int j = 0; j < 8; ++j) {
            int ww = q * 8 + j - 3;
            float f = (rok && (unsigned)ww < 36u) ? src[ww] : 0.f;
            v.s[j] = f2bf(f);
        }
        *(uint4*)(xp + idx * 8) = v.u;
        return;
    }
    if (bid < 2521) {
        int e = (bid - 1737) * 256 + tid;
        if (e < 200704) {
            int k = e % 3136, co = e / 3136;
            int kw = k & 7, kh = (k >> 3) & 7, kdt = k >> 6;
            int kt = kdt / 7, kd = kdt % 7;
            float v = 0.f;
            if (kh < 7 && kw < 7)
                v = c1w[(size_t)(kt * 64 + co) * 343 + kd * 49 + kh * 7 + kw];
            o1[e] = f2bf(v);
        }
        return;
    }

    int wb = bid - 2521; // < 3072
    const float* in; ushortT* out; int Ci, Co;
    int base;
    if (wb < 192) {
        if (wb < 48) {
            if (wb < 24) { in = w11; out = o11; Ci = 64; Co = 64; base = 0; }
            else         { in = w12; out = o12; Ci = 64; Co = 64; base = 24; }
        } else if (wb < 96) { in = w21; out = o21; Ci = 64;  Co = 128; base = 48; }
        else                { in = w22; out = o22; Ci = 128; Co = 128; base = 96; }
    } else if (wb < 768) {
        if (wb < 384) { in = w31; out = o31; Ci = 128; Co = 256; base = 192; }
        else          { in = w32; out = o32; Ci = 256; Co = 256; base = 384; }
    } else {
        if (wb < 1536) { in = w41; out = o41; Ci = 256; Co = 512; base = 768; }
        else           { in = w42; out = o42; Ci = 512; Co = 512; base = 1536; }
    }
    int lb = wb - base;
    int nCb = Co >> 4, nKb = Ci >> 5;
    int per_i = nCb * nKb;
    int i = lb / per_i;
    int r2 = lb - i * per_i;
    int cb = r2 / nKb, kb = r2 - cb * nKb;

    size_t costride = (size_t)Ci * 27;
    ushortT* dst0 = out + (((size_t)(i * 27) * nCb + cb) * nKb + kb) * 512;
    size_t tapstride = (size_t)nCb * nKb * 512;

    for (int ph = 0; ph < 2; ++ph) {
        const float* src0 = in + ((size_t)(i * Co + cb * 16) * Ci + kb * 32 + ph * 16) * 27;
        for (int e = tid; e < 1728; e += 256) {
            int cl = e / 108, q = e - cl * 108;
            *(float4*)(tile + cl * 435 + 4 * q) = *(const float4*)(src0 + cl * costride + 4 * q);
        }
        __syncthreads();
        for (int e = tid; e < 864; e += 256) {
            int tap = e >> 5, wl = e & 31;
            int gh = wl >> 4, l15 = wl & 15;
            union { ushortT s[8]; uint4 u; } v;
#pragma unroll
            for (int j = 0; j < 8; ++j)
                v.s[j] = f2bf(tile[l15 * 435 + (gh * 8 + j) * 27 + tap]);
            *(uint4*)(dst0 + (size_t)tap * tapstride + (ph * 32 + wl) * 8) = v.u;
        }
        __syncthreads();
    }
}

// ---------------- mega: conv1 MFMA, stride-26 LDS + XCD swizzle ----------------
// Wave repartition vs r17: each wave = ALL 4 co-tiles (c=4) x 3 m-subtiles (wv picks m-half)
// -> per khq step: 12 ds_read + 12 MFMA (1:1, was 24:12). A loads 4/step (L1-resident).
__global__ __launch_bounds__(128) void mega_kernel(
        const ushortT* __restrict__ xp, const ushortT* __restrict__ aw,
        ushortT* __restrict__ outc1) {
    __shared__ __align__(16) ushortT smem[12376]; // 2 x (238 rows x 26)
    int bid = blockIdx.x, tid = threadIdx.x;

    {
        int xcd = bid & 7, loc = bid >> 3;
        bid = (xcd < 6) ? (xcd * 169 + loc) : (1014 + (xcd - 6) * 168 + loc);
    }

    int wt = bid % 5; int r = bid / 5;
    int ht = r % 5; r /= 5;
    int dt = r % 3; int ot = r / 3;
    int ow0 = wt * 4, oh0 = ht * 4, od0 = dt * 6;
    int gw0 = 2 * ow0, gh0 = 2 * oh0, gd0 = 2 * od0;

    int lane = tid & 63, wv = tid >> 6;
    int l15 = lane & 15, g = lane >> 4;
    int dh = l15 >> 2, dw = l15 & 3;
    int mo = wv * 3; // wave's m-base (od sub-offset)

    const ushortT* ap0 = aw + (size_t)l15 * 3136 + g * 8;
    const ushortT* ap1 = ap0 + 16 * 3136;
    const ushortT* ap2 = ap0 + 32 * 3136;
    const ushortT* ap3 = ap0 + 48 * 3136;

    ushortT* curb = smem;
    ushortT* nxtb = smem + 6188;

    auto stage = [&](ushortT* buf, int kt) {
        int gt = 2 * ot + kt;
        for (int rr = tid; rr < 238; rr += 128) {
            int ld = rr / 14, lh = rr - ld * 14;
            const ushortT* s = xp +
                ((size_t)((gt * 42 + gd0 + ld) * 42 + gh0 + lh)) * 48 + gw0;
            uint4 a = *(const uint4*)s;
            uint4 b = *(const uint4*)(s + 8);
            unsigned* d = (unsigned*)buf + rr * 13;
            d[0] = a.x; d[1] = a.y; d[2] = a.z; d[3] = a.w;
            d[4] = b.x; d[5] = b.y; d[6] = b.z; d[7] = b.w;
        }
    };

    f32x4 acc[4][3];
#pragma unroll
    for (int c = 0; c < 4; ++c)
#pragma unroll
        for (int m = 0; m < 3; ++m) acc[c][m] = (f32x4){0.f, 0.f, 0.f, 0.f};

    stage(curb, 0);
    __syncthreads();

    int lhl = (2 * dh + g) * 26 + 2 * dw;
    int kidx = 0;
    for (int kt = 0; kt < 7; ++kt) {
        if (kt < 6) stage(nxtb, kt + 1);
        for (int kd = 0; kd < 7; ++kd) {
            int C0 = kd * 364 + lhl + mo * 728;
#pragma unroll
            for (int khq = 0; khq < 2; ++khq) {
                bf16x8 a0 = *(const bf16x8*)(ap0 + kidx);
                bf16x8 a1 = *(const bf16x8*)(ap1 + kidx);
                bf16x8 a2 = *(const bf16x8*)(ap2 + kidx);
                bf16x8 a3 = *(const bf16x8*)(ap3 + kidx);
                kidx += 32;
                int C = C0 + khq * 104;
#pragma unroll
                for (int m = 0; m < 3; ++m) {
                    int off = C + m * 728;
                    union { unsigned u[4]; bf16x8 v; } bb;
                    bb.u[0] = *(const unsigned*)(curb + off);
                    bb.u[1] = *(const unsigned*)(curb + off + 2);
                    bb.u[2] = *(const unsigned*)(curb + off + 4);
                    bb.u[3] = *(const unsigned*)(curb + off + 6);
                    acc[0][m] = __builtin_amdgcn_mfma_f32_16x16x32_bf16(a0, bb.v, acc[0][m], 0, 0, 0);
                    acc[1][m] = __builtin_amdgcn_mfma_f32_16x16x32_bf16(a1, bb.v, acc[1][m], 0, 0, 0);
                    acc[2][m] = __builtin_amdgcn_mfma_f32_16x16x32_bf16(a2, bb.v, acc[2][m], 0, 0, 0);
                    acc[3][m] = __builtin_amdgcn_mfma_f32_16x16x32_bf16(a3, bb.v, acc[3][m], 0, 0, 0);
                }
            }
        }
        __syncthreads();
        ushortT* t2 = curb; curb = nxtb; nxtb = t2;
    }

    int oh = oh0 + dh, ow = ow0 + dw;
    if (oh < 18 && ow < 18) {
#pragma unroll
        for (int m = 0; m < 3; ++m) {
            int od = od0 + mo + m; // od0 <= 12, mo+m <= 5 -> od <= 17
            int pos = ((ot * 18 + od) * 18 + oh) * 18 + ow;
#pragma unroll
            for (int c = 0; c < 4; ++c) {
                ushort4 st;
                st.x = f2bf(fmaxf(acc[c][m][0], 0.f));
                st.y = f2bf(fmaxf(acc[c][m][1], 0.f));
                st.z = f2bf(fmaxf(acc[c][m][2], 0.f));
                st.w = f2bf(fmaxf(acc[c][m][3], 0.f));
                *(ushort4*)(outc1 + (size_t)pos * 64 + c * 16 + g * 4) = st;
            }
        }
    }
}

// ---------------- maxpool 3^4 s2 p1: bf16 [18^4][64] -> bf16 [9^4][64]; zero-fills zb ------
__global__ void maxpool2(const ushortT* __restrict__ in, ushortT* __restrict__ out,
                         ushortT* __restrict__ zb) {
    int idx = blockIdx.x * 256 + threadIdx.x;
    if (idx < 128) zb[idx] = 0;
    if (idx >= 6561 * 16) return;
    int c4 = idx & 15;
    int p = idx >> 4;
    int ow = p % 9; int t = p / 9;
    int oh = t % 9; t /= 9;
    int od = t % 9; int ot = t / 9;
    ushort4 m = {0, 0, 0, 0};
    for (int kt = 0; kt < 3; ++kt) { int it = 2 * ot + kt - 1; if ((unsigned)it >= 18u) continue;
        for (int kd = 0; kd < 3; ++kd) { int id = 2 * od + kd - 1; if ((unsigned)id >= 18u) continue;
            for (int kh = 0; kh < 3; ++kh) { int ih = 2 * oh + kh - 1; if ((unsigned)ih >= 18u) continue;
                int rb = ((it * 18 + id) * 18 + ih) * 18;
                for (int kw = 0; kw < 3; ++kw) { int iw = 2 * ow + kw - 1; if ((unsigned)iw >= 18u) continue;
                    ushort4 v = *(const ushort4*)(in + (size_t)(rb + iw) * 64 + c4 * 4);
                    m.x = v.x > m.x ? v.x : m.x;
                    m.y = v.y > m.y ? v.y : m.y;
                    m.z = v.z > m.z ? v.z : m.z;
                    m.w = v.w > m.w ? v.w : m.w;
                }
            }
        }
    }
    *(ushort4*)(out + (size_t)p * 64 + c4 * 4) = m;
}

// ---------------- MFMA implicit-GEMM residual conv, packed A-tiles ----------------
// TS=1: full 27-tap loop (opt fused epilogue / merged dw). TS=9: tap-split, z = ks*9 + ts.
template <int KC, int FUSE, int TS>
__global__ void convmfma(const ushortT* __restrict__ xb, const ushortT* __restrict__ wt,
                         const float* __restrict__ bias, const ushortT* __restrict__ res,
                         ushortT* __restrict__ outb, float* __restrict__ part,
                         const ushortT* __restrict__ zq,
                         int Ci, int Co, int T, int O, int stride, int chunk,
                         const float* __restrict__ dwW, ushortT* __restrict__ dwOut) {
    if (dwW && blockIdx.y == (unsigned)(Co >> 6)) {
        int O2 = O * O, O3 = O2 * O, O4 = O3 * O;
        int total = Co * O4;
        int sthr = gridDim.x * gridDim.z * 256;
        for (int idx = (blockIdx.z * gridDim.x + blockIdx.x) * 256 + threadIdx.x;
             idx < total; idx += sthr) {
            int co = idx % Co;
            int pos = idx / Co;
            int ow = pos % O, oh = (pos / O) % O, od = (pos / O2) % O, ot = pos / O3;
            int ip = (((2 * ot) * T + 2 * od) * T + 2 * oh) * T + 2 * ow;
            const ushortT* xpp = xb + (size_t)ip * Ci;
            const float* wp = dwW + (size_t)co * Ci;
            float acc = 0.f;
            for (int c8 = 0; c8 < Ci; c8 += 8) {
                uint4 xv = *(const uint4*)(xpp + c8);
                float4 w0 = *(const float4*)(wp + c8);
                float4 w1 = *(const float4*)(wp + c8 + 4);
                acc = fmaf(bf2f((unsigned short)(xv.x & 0xffff)), w0.x, acc);
                acc = fmaf(bf2f((unsigned short)(xv.x >> 16)),    w0.y, acc);
                acc = fmaf(bf2f((unsigned short)(xv.y & 0xffff)), w0.z, acc);
                acc = fmaf(bf2f((unsigned short)(xv.y >> 16)),    w0.w, acc);
                acc = fmaf(bf2f((unsigned short)(xv.z & 0xffff)), w1.x, acc);
                acc = fmaf(bf2f((unsigned short)(xv.z >> 16)),    w1.y, acc);
                acc = fmaf(bf2f((unsigned short)(xv.w & 0xffff)), w1.z, acc);
                acc = fmaf(bf2f((unsigned short)(xv.w >> 16)),    w1.w, acc);
            }
            dwOut[idx] = f2bf(acc);
        }
        return;
    }

    int lane = threadIdx.x & 63;
    int wv = threadIdx.x >> 6;
    int p0 = blockIdx.x * 16;
    int cb = blockIdx.y * 4 + wv;
    int co0 = cb * 16;
    int zz = blockIdx.z;
    int ks, ts;
    if (TS > 1) { ks = zz / TS; ts = zz % TS; } else { ks = zz; ts = 0; }
    int cbase = ks * chunk;
    int kb0 = cbase >> 5;
    size_t nCb = Co >> 4, nKb = Ci >> 5;

    int pn = p0 + (lane & 15);
    int O2 = O * O, O3 = O2 * O, O4 = O3 * O;
    bool pv = pn < O4;
    int pc = pv ? pn : 0;
    int ow = pc % O, oh = (pc / O) % O, od = (pc / O2) % O, ot = pc / O3;
    int g = lane >> 4;
    int kl = cbase + g * 8;

    const ushortT* zp = zq + g * 8;

    f32x4 acc[4];
#pragma unroll
    for (int a = 0; a < 4; ++a) acc[a] = (f32x4){0.f, 0.f, 0.f, 0.f};

    int itb = ot * stride - 1, idb = od * stride - 1, ihb = oh * stride - 1, iwb = ow * stride - 1;

    if (TS == 1) {
#pragma unroll
        for (int i = 0; i < 3; ++i) {
            int it = itb + i;
            bool vt = pv && ((unsigned)it < (unsigned)T);
#pragma unroll
            for (int kd = 0; kd < 3; ++kd) {
                int id = idb + kd;
                bool vdd = vt && ((unsigned)id < (unsigned)T);
                int btd = (it * T + id) * T;
#pragma unroll
                for (int kh = 0; kh < 3; ++kh) {
                    int ih = ihb + kh;
                    bool vh = vdd && ((unsigned)ih < (unsigned)T);
#pragma unroll
                    for (int kw = 0; kw < 3; ++kw) {
                        int iw = iwb + kw;
                        bool v = vh && ((unsigned)iw < (unsigned)T);
                        int ip = (btd + ih) * T + iw;
                        const int tap = (i * 9 + kd * 3 + kh) * 3 + kw;
                        const ushortT* bp = v ? (xb + (size_t)ip * Ci + kl) : zp;
                        const ushortT* ap = wt + (((size_t)tap * nCb + cb) * nKb + kb0) * 512
                                            + lane * 8;
#pragma unroll
                        for (int kc = 0; kc < KC; ++kc) {
                            bf16x8 av = *(const bf16x8*)(ap + kc * 512);
                            bf16x8 bv = *(const bf16x8*)(bp + kc * 32);
                            acc[(tap * KC + kc) & 3] =
                                __builtin_amdgcn_mfma_f32_16x16x32_bf16(av, bv,
                                    acc[(tap * KC + kc) & 3], 0, 0, 0);
                        }
                    }
                }
            }
        }
    } else {
        int i = ts / 3, kd = ts % 3;
        int it = itb + i;
        int id = idb + kd;
        bool vt = pv && ((unsigned)it < (unsigned)T) && ((unsigned)id < (unsigned)T);
        int btd = (it * T + id) * T;
        int tapb = i * 27 + kd * 9;
#pragma unroll
        for (int kh = 0; kh < 3; ++kh) {
            int ih = ihb + kh;
            bool vh = vt && ((unsigned)ih < (unsigned)T);
#pragma unroll
            for (int kw = 0; kw < 3; ++kw) {
                int iw = iwb + kw;
                bool v = vh && ((unsigned)iw < (unsigned)T);
                int ip = (btd + ih) * T + iw;
                int tap = tapb + kh * 3 + kw;
                const ushortT* bp = v ? (xb + (size_t)ip * Ci + kl) : zp;
                const ushortT* ap = wt + (((size_t)tap * nCb + cb) * nKb + kb0) * 512
                                    + lane * 8;
#pragma unroll
                for (int kc = 0; kc < KC; ++kc) {
                    bf16x8 av = *(const bf16x8*)(ap + kc * 512);
                    bf16x8 bv = *(const bf16x8*)(bp + kc * 32);
                    acc[(kh * 3 + kw + kc) & 3] =
                        __builtin_amdgcn_mfma_f32_16x16x32_bf16(av, bv,
                            acc[(kh * 3 + kw + kc) & 3], 0, 0, 0);
                }
            }
        }
    }

    if (!pv) return;
    f32x4 asum;
#pragma unroll
    for (int r = 0; r < 4; ++r)
        asum[r] = (acc[0][r] + acc[1][r]) + (acc[2][r] + acc[3][r]);
    int cob = co0 + g * 4;
    if (FUSE) {
        float bb[4] = {0.f, 0.f, 0.f, 0.f};
        for (int i = 0; i < 3; ++i) {
            int it = itb + i;
            if ((unsigned)it < (unsigned)T) {
#pragma unroll
                for (int rr = 0; rr < 4; ++rr) bb[rr] += bias[i * Co + cob + rr];
            }
        }
        float rv[4] = {0.f, 0.f, 0.f, 0.f};
        if (res) {
            ushort4 r4 = *(const ushort4*)(res + (size_t)pn * Co + cob);
            rv[0] = bf2f(r4.x); rv[1] = bf2f(r4.y); rv[2] = bf2f(r4.z); rv[3] = bf2f(r4.w);
        }
        ushort4 st;
        st.x = f2bf(fmaxf(asum[0] + bb[0] + rv[0], 0.f));
        st.y = f2bf(fmaxf(asum[1] + bb[1] + rv[1], 0.f));
        st.z = f2bf(fmaxf(asum[2] + bb[2] + rv[2], 0.f));
        st.w = f2bf(fmaxf(asum[3] + bb[3] + rv[3], 0.f));
        *(ushort4*)(outb + (size_t)pn * Co + cob) = st;
    } else {
        *(f32x4*)(part + ((size_t)zz * O4 + pn) * Co + cob) = asum;
    }
}

// ---------------- finalize: sum z-slices + T-valid bias + res + relu ----------------
__global__ void finalize_k(const float* __restrict__ part, int KS,
                           const float* __restrict__ bias, const ushortT* __restrict__ res,
                           ushortT* __restrict__ outb, int Co, int O4, int T, int O, int stride,
                           int total) {
    int idx = blockIdx.x * 256 + threadIdx.x;
    if (idx >= total) return;
    int co = idx % Co;
    int pos = idx / Co;
    float v = 0.f;
    for (int z = 0; z < KS; ++z) v += part[((size_t)z * O4 + pos) * Co + co];
    int ot = pos / (O * O * O);
    for (int i = 0; i < 3; ++i) {
        int it = ot * stride + i - 1;
        if ((unsigned)it < (unsigned)T) v += bias[i * Co + co];
    }
    if (res) v += bf2f(res[idx]);
    outb[idx] = f2bf(fmaxf(v, 0.f));
}

// ---------------- avgpool 2^4 + FC (512 -> 1) ----------------
__global__ void avgfc2(const ushortT* __restrict__ xin, const float* __restrict__ fw,
                       const float* __restrict__ fb, float* __restrict__ out) {
    __shared__ float ls[8];
    int t = threadIdx.x; // 512
    float s = 0.f;
#pragma unroll
    for (int pp = 0; pp < 16; ++pp) s += bf2f(xin[pp * 512 + t]);
    s = s * (1.f / 16.f) * fw[t];
    for (int off = 32; off > 0; off >>= 1) s += __shfl_xor(s, off, 64);
    if ((t & 63) == 0) ls[t >> 6] = s;
    __syncthreads();
    if (t == 0) {
        float tot = 0.f;
#pragma unroll
        for (int i = 0; i < 8; ++i) tot += ls[i];
        out[0] = tot + fb[0];
    }
}

extern "C" void kernel_launch(void* const* d_in, const int* in_sizes, int n_in,
                              void* d_out, int out_size, void* d_ws, size_t ws_size,
                              hipStream_t stream) {
    const float* x       = (const float*)d_in[0];
    const float* conv1_w = (const float*)d_in[1];
    const float* l1_w1 = (const float*)d_in[2];
    const float* l1_b1 = (const float*)d_in[3];
    const float* l1_w2 = (const float*)d_in[4];
    const float* l1_b2 = (const float*)d_in[5];
    const float* l2_w1 = (const float*)d_in[6];
    const float* l2_b1 = (const float*)d_in[7];
    const float* l2_w2 = (const float*)d_in[8];
    const float* l2_b2 = (const float*)d_in[9];
    const float* l2_dw = (const float*)d_in[10];
    const float* l3_w1 = (const float*)d_in[11];
    const float* l3_b1 = (const float*)d_in[12];
    const float* l3_w2 = (const float*)d_in[13];
    const float* l3_b2 = (const float*)d_in[14];
    const float* l3_dw = (const float*)d_in[15];
    const float* l4_w1 = (const float*)d_in[16];
    const float* l4_b1 = (const float*)d_in[17];
    const float* l4_w2 = (const float*)d_in[18];
    const float* l4_b2 = (const float*)d_in[19];
    const float* l4_dw = (const float*)d_in[20];
    const float* fc_w  = (const float*)d_in[21];
    const float* fc_b  = (const float*)d_in[22];
    float* outp = (float*)d_out;

    char* bp = (char*)d_ws;
    auto alloc = [&](size_t bytes) {
        char* r = bp;
        bp += (bytes + 255) & ~(size_t)255;
        return (void*)r;
    };
    ushortT* A16 = (ushortT*)alloc(6718464ull * 2); // conv1 out bf16 [18^4][64]
    ushortT* XP  = (ushortT*)alloc(3556224ull * 2); // padded bf16 x [42][42][42][48]
    ushortT* Aw1 = (ushortT*)alloc(200704ull * 2);
    ushortT* X0 = (ushortT*)alloc(419904ull * 2);
    ushortT* Y1 = (ushortT*)alloc(419904ull * 2);
    ushortT* X1 = (ushortT*)alloc(419904ull * 2);
    ushortT* Y2 = (ushortT*)alloc(80000ull * 2);
    ushortT* R2 = (ushortT*)alloc(80000ull * 2);
    ushortT* X2 = (ushortT*)alloc(80000ull * 2);
    ushortT* Y3 = (ushortT*)alloc(20736ull * 2);
    ushortT* R3 = (ushortT*)alloc(20736ull * 2);
    ushortT* X3 = (ushortT*)alloc(20736ull * 2);
    ushortT* Y4 = (ushortT*)alloc(8192ull * 2);
    ushortT* R4 = (ushortT*)alloc(8192ull * 2);
    ushortT* X4 = (ushortT*)alloc(8192ull * 2);
    ushortT* W11 = (ushortT*)alloc(331776ull * 2);
    ushortT* W12 = (ushortT*)alloc(331776ull * 2);
    ushortT* W21 = (ushortT*)alloc(663552ull * 2);
    ushortT* W22 = (ushortT*)alloc(1327104ull * 2);
    ushortT* W31 = (ushortT*)alloc(2654208ull * 2);
    ushortT* W32 = (ushortT*)alloc(5308416ull * 2);
    ushortT* W41 = (ushortT*)alloc(10616832ull * 2);
    ushortT* W42 = (ushortT*)alloc(21233664ull * 2);
    float* P    = (float*)alloc(1492992ull * 4);   // max: l3c2 72 x 81 x 256
    ushortT* ZB = (ushortT*)alloc(256);
    if ((size_t)(bp - (char*)d_ws) > ws_size) return; // workspace too small: fail cleanly

    // 1) pad/convert x + conv1 weights + packed residual weight prep
    prep0<<<5593, 256, 0, stream>>>(x, conv1_w,
                                    l1_w1, l1_w2, l2_w1, l2_w2, l3_w1, l3_w2, l4_w1, l4_w2,
                                    XP, Aw1,
                                    W11, W12, W21, W22, W31, W32, W41, W42);

    // 2) conv1 MFMA (stride-26 LDS + XCD swizzle; c=4 x m=3 wave split)
    mega_kernel<<<1350, 128, 0, stream>>>(XP, Aw1, A16);

    // 3) stem pool (+ zero ZB)
    maxpool2<<<411, 256, 0, stream>>>(A16, X0, ZB);

    // 4) layer1
    convmfma<2, 1, 1><<<dim3(411, 1, 1), 256, 0, stream>>>(
        X0, W11, l1_b1, nullptr, Y1, nullptr, ZB, 64, 64, 9, 9, 1, 64, nullptr, nullptr);
    convmfma<2, 1, 1><<<dim3(411, 1, 1), 256, 0, stream>>>(
        Y1, W12, l1_b2, X0, X1, nullptr, ZB, 64, 64, 9, 9, 1, 64, nullptr, nullptr);

    // 5) layer2 (dw merged into c1)
    convmfma<2, 1, 1><<<dim3(40, 3, 1), 256, 0, stream>>>(
        X1, W21, l2_b1, nullptr, Y2, nullptr, ZB, 64, 128, 9, 5, 2, 64, l2_dw, R2);
    convmfma<4, 1, 1><<<dim3(40, 2, 1), 256, 0, stream>>>(
        Y2, W22, l2_b2, R2, X2, nullptr, ZB, 128, 128, 5, 5, 1, 128, nullptr, nullptr);

    // 6) layer3: c1 KS=4 x TS=9 (+dw); c2 KS=8 x TS=9
    convmfma<1, 0, 9><<<dim3(6, 5, 36), 256, 0, stream>>>(
        X2, W31, nullptr, nullptr, nullptr, P, ZB, 128, 256, 5, 3, 2, 32, l3_dw, R3);
    finalize_k<<<81, 256, 0, stream>>>(P, 36, l3_b1, nullptr, Y3, 256, 81, 5, 3, 2, 20736);
    convmfma<1, 0, 9><<<dim3(6, 4, 72), 256, 0, stream>>>(
        Y3, W32, nullptr, nullptr, nullptr, P, ZB, 256, 256, 3, 3, 1, 32, nullptr, nullptr);
    finalize_k<<<81, 256, 0, stream>>>(P, 72, l3_b2, R3, X3, 256, 81, 3, 3, 1, 20736);

    // 7) layer4: c1 KS=8 x TS=9 (+dw); c2 KS=16 x TS=9
    convmfma<1, 0, 9><<<dim3(1, 9, 72), 256, 0, stream>>>(
        X3, W41, nullptr, nullptr, nullptr, P, ZB, 256, 512, 3, 2, 2, 32, l4_dw, R4);
    finalize_k<<<32, 256, 0, stream>>>(P, 72, l4_b1, nullptr, Y4, 512, 16, 3, 2, 2, 8192);
    convmfma<1, 0, 9><<<dim3(1, 8, 144), 256, 0, stream>>>(
        Y4, W42, nullptr, nullptr, nullptr, P, ZB, 512, 512, 2, 2, 1, 32, nullptr, nullptr);
    finalize_k<<<32, 256, 0, stream>>>(P, 144, l4_b2, R4, X4, 512, 16, 2, 2, 1, 8192);

    // 8) head
    avgfc2<<<1, 512, 0, stream>>>(X4, fc_w, fc_b, outp);
}

// Round 20
// 474.158 us; speedup vs baseline: 1.8712x; 1.1288x over previous
//
#include <hip/hip_runtime.h>

typedef __bf16 bf16x8 __attribute__((ext_vector_type(8)));
typedef float f32x4 __attribute__((ext_vector_type(4)));
typedef unsigned short ushortT;

__device__ __forceinline__ unsigned short f2bf(float f) {
    unsigned u = __float_as_uint(f);
    u += 0x7fffu + ((u >> 16) & 1u);
    return (unsigned short)(u >> 16);
}
__device__ __forceinline__ float bf2f(unsigned short h) {
    return __uint_as_float((unsigned)h << 16);
}

// ---------------- prep0: xpad + conv1 weights + A-tile-packed residual weight prep ---------
// (validated r17: ci-phased 27.8KB LDS transpose, contiguous 512B tap-runs on the write side)
__global__ __launch_bounds__(256) void prep0(const float* __restrict__ x,
                                             const float* __restrict__ c1w,
                                             const float* __restrict__ w11, const float* __restrict__ w12,
                                             const float* __restrict__ w21, const float* __restrict__ w22,
                                             const float* __restrict__ w31, const float* __restrict__ w32,
                                             const float* __restrict__ w41, const float* __restrict__ w42,
                                             ushortT* __restrict__ xp,
                                             ushortT* __restrict__ o1,
                                             ushortT* __restrict__ o11, ushortT* __restrict__ o12,
                                             ushortT* __restrict__ o21, ushortT* __restrict__ o22,
                                             ushortT* __restrict__ o31, ushortT* __restrict__ o32,
                                             ushortT* __restrict__ o41, ushortT* __restrict__ o42) {
    __shared__ float tile[6960]; // 16 x 435 f32 = 27,840 B
    int bid = blockIdx.x, tid = threadIdx.x;
    if (bid < 1737) {
        long idx = (long)bid * 256 + tid;
        if (idx >= 444528L) return;
        int q = (int)(idx % 6); long r = idx / 6;
        int h = (int)(r % 42); r /= 42;
        int d = (int)(r % 42); int t = (int)(r / 42);
        int tt = t - 3, dd = d - 3, hh = h - 3;
        bool rok = ((unsigned)tt < 36u) && ((unsigned)dd < 36u) && ((unsigned)hh < 36u);
        const float* src = x + (((long)tt * 36 + dd) * 36 + hh) * 36;
        union { ushortT s[8]; uint4 u; } v;
#pragma unroll
        for (int j = 0; j < 8; ++j) {
            int ww = q * 8 + j - 3;
            float f = (rok && (unsigned)ww < 36u) ? src[ww] : 0.f;
            v.s[j] = f2bf(f);
        }
        *(uint4*)(xp + idx * 8) = v.u;
        return;
    }
    if (bid < 2521) {
        int e = (bid - 1737) * 256 + tid;
        if (e < 200704) {
            int k = e % 3136, co = e / 3136;
            int kw = k & 7, kh = (k >> 3) & 7, kdt = k >> 6;
            int kt = kdt / 7, kd = kdt % 7;
            float v = 0.f;
            if (kh < 7 && kw < 7)
                v = c1w[(size_t)(kt * 64 + co) * 343 + kd * 49 + kh * 7 + kw];
            o1[e] = f2bf(v);
        }
        return;
    }

    int wb = bid - 2521; // < 3072
    const float* in; ushortT* out; int Ci, Co;
    int base;
    if (wb < 192) {
        if (wb < 48) {
            if (wb < 24) { in = w11; out = o11; Ci = 64; Co = 64; base = 0; }
            else         { in = w12; out = o12; Ci = 64; Co = 64; base = 24; }
        } else if (wb < 96) { in = w21; out = o21; Ci = 64;  Co = 128; base = 48; }
        else                { in = w22; out = o22; Ci = 128; Co = 128; base = 96; }
    } else if (wb < 768) {
        if (wb < 384) { in = w31; out = o31; Ci = 128; Co = 256; base = 192; }
        else          { in = w32; out = o32; Ci = 256; Co = 256; base = 384; }
    } else {
        if (wb < 1536) { in = w41; out = o41; Ci = 256; Co = 512; base = 768; }
        else           { in = w42; out = o42; Ci = 512; Co = 512; base = 1536; }
    }
    int lb = wb - base;
    int nCb = Co >> 4, nKb = Ci >> 5;
    int per_i = nCb * nKb;
    int i = lb / per_i;
    int r2 = lb - i * per_i;
    int cb = r2 / nKb, kb = r2 - cb * nKb;

    size_t costride = (size_t)Ci * 27;
    ushortT* dst0 = out + (((size_t)(i * 27) * nCb + cb) * nKb + kb) * 512;
    size_t tapstride = (size_t)nCb * nKb * 512;

    for (int ph = 0; ph < 2; ++ph) {
        const float* src0 = in + ((size_t)(i * Co + cb * 16) * Ci + kb * 32 + ph * 16) * 27;
        for (int e = tid; e < 1728; e += 256) {
            int cl = e / 108, q = e - cl * 108;
            *(float4*)(tile + cl * 435 + 4 * q) = *(const float4*)(src0 + cl * costride + 4 * q);
        }
        __syncthreads();
        for (int e = tid; e < 864; e += 256) {
            int tap = e >> 5, wl = e & 31;
            int gh = wl >> 4, l15 = wl & 15;
            union { ushortT s[8]; uint4 u; } v;
#pragma unroll
            for (int j = 0; j < 8; ++j)
                v.s[j] = f2bf(tile[l15 * 435 + (gh * 8 + j) * 27 + tap]);
            *(uint4*)(dst0 + (size_t)tap * tapstride + (ph * 32 + wl) * 8) = v.u;
        }
        __syncthreads();
    }
}

// ---------------- mega: conv1 MFMA, stride-26 LDS + bijective XCD swizzle (r17 exact) ------
// Wave = 2 co-tiles x 6 m-subtiles: 2 A-glob loads + 24 ds_read per khq step — the validated
// latency/issue balance (r19's 4-A variant exposed A latency and regressed).
__global__ __launch_bounds__(128) void mega_kernel(
        const ushortT* __restrict__ xp, const ushortT* __restrict__ aw,
        ushortT* __restrict__ outc1) {
    __shared__ __align__(16) ushortT smem[12376]; // 2 x (238 rows x 26)
    int bid = blockIdx.x, tid = threadIdx.x;

    {
        int xcd = bid & 7, loc = bid >> 3;
        bid = (xcd < 6) ? (xcd * 169 + loc) : (1014 + (xcd - 6) * 168 + loc);
    }

    int wt = bid % 5; int r = bid / 5;
    int ht = r % 5; r /= 5;
    int dt = r % 3; int ot = r / 3;
    int ow0 = wt * 4, oh0 = ht * 4, od0 = dt * 6;
    int gw0 = 2 * ow0, gh0 = 2 * oh0, gd0 = 2 * od0;

    int lane = tid & 63, wv = tid >> 6;
    int l15 = lane & 15, g = lane >> 4;
    int dh = l15 >> 2, dw = l15 & 3;

    const ushortT* ap0 = aw + (size_t)(wv * 32 + l15) * 3136 + g * 8;
    const ushortT* ap1 = ap0 + 16 * 3136;

    ushortT* curb = smem;
    ushortT* nxtb = smem + 6188;

    auto stage = [&](ushortT* buf, int kt) {
        int gt = 2 * ot + kt;
        for (int rr = tid; rr < 238; rr += 128) {
            int ld = rr / 14, lh = rr - ld * 14;
            const ushortT* s = xp +
                ((size_t)((gt * 42 + gd0 + ld) * 42 + gh0 + lh)) * 48 + gw0;
            uint4 a = *(const uint4*)s;
            uint4 b = *(const uint4*)(s + 8);
            unsigned* d = (unsigned*)buf + rr * 13;
            d[0] = a.x; d[1] = a.y; d[2] = a.z; d[3] = a.w;
            d[4] = b.x; d[5] = b.y; d[6] = b.z; d[7] = b.w;
        }
    };

    f32x4 acc[2][6];
#pragma unroll
    for (int c = 0; c < 2; ++c)
#pragma unroll
        for (int m = 0; m < 6; ++m) acc[c][m] = (f32x4){0.f, 0.f, 0.f, 0.f};

    stage(curb, 0);
    __syncthreads();

    int lhl = (2 * dh + g) * 26 + 2 * dw;
    int kidx = 0;
    for (int kt = 0; kt < 7; ++kt) {
        if (kt < 6) stage(nxtb, kt + 1);
        for (int kd = 0; kd < 7; ++kd) {
            int C0 = kd * 364 + lhl;
#pragma unroll
            for (int khq = 0; khq < 2; ++khq) {
                bf16x8 a0 = *(const bf16x8*)(ap0 + kidx);
                bf16x8 a1 = *(const bf16x8*)(ap1 + kidx);
                kidx += 32;
                int C = C0 + khq * 104;
#pragma unroll
                for (int m = 0; m < 6; ++m) {
                    int off = C + m * 728;
                    union { unsigned u[4]; bf16x8 v; } bb;
                    bb.u[0] = *(const unsigned*)(curb + off);
                    bb.u[1] = *(const unsigned*)(curb + off + 2);
                    bb.u[2] = *(const unsigned*)(curb + off + 4);
                    bb.u[3] = *(const unsigned*)(curb + off + 6);
                    acc[0][m] = __builtin_amdgcn_mfma_f32_16x16x32_bf16(a0, bb.v, acc[0][m], 0, 0, 0);
                    acc[1][m] = __builtin_amdgcn_mfma_f32_16x16x32_bf16(a1, bb.v, acc[1][m], 0, 0, 0);
                }
            }
        }
        __syncthreads();
        ushortT* t2 = curb; curb = nxtb; nxtb = t2;
    }

    int oh = oh0 + dh, ow = ow0 + dw;
    if (oh < 18 && ow < 18) {
#pragma unroll
        for (int m = 0; m < 6; ++m) {
            int od = od0 + m;
            int pos = ((ot * 18 + od) * 18 + oh) * 18 + ow;
#pragma unroll
            for (int c = 0; c < 2; ++c) {
                ushort4 st;
                st.x = f2bf(fmaxf(acc[c][m][0], 0.f));
                st.y = f2bf(fmaxf(acc[c][m][1], 0.f));
                st.z = f2bf(fmaxf(acc[c][m][2], 0.f));
                st.w = f2bf(fmaxf(acc[c][m][3], 0.f));
                *(ushort4*)(outc1 + (size_t)pos * 64 + wv * 32 + c * 16 + g * 4) = st;
            }
        }
    }
}

// ---------------- maxpool 3^4 s2 p1: bf16 [18^4][64] -> bf16 [9^4][64]; zero-fills zb ------
__global__ void maxpool2(const ushortT* __restrict__ in, ushortT* __restrict__ out,
                         ushortT* __restrict__ zb) {
    int idx = blockIdx.x * 256 + threadIdx.x;
    if (idx < 128) zb[idx] = 0;
    if (idx >= 6561 * 16) return;
    int c4 = idx & 15;
    int p = idx >> 4;
    int ow = p % 9; int t = p / 9;
    int oh = t % 9; t /= 9;
    int od = t % 9; int ot = t / 9;
    ushort4 m = {0, 0, 0, 0};
    for (int kt = 0; kt < 3; ++kt) { int it = 2 * ot + kt - 1; if ((unsigned)it >= 18u) continue;
        for (int kd = 0; kd < 3; ++kd) { int id = 2 * od + kd - 1; if ((unsigned)id >= 18u) continue;
            for (int kh = 0; kh < 3; ++kh) { int ih = 2 * oh + kh - 1; if ((unsigned)ih >= 18u) continue;
                int rb = ((it * 18 + id) * 18 + ih) * 18;
                for (int kw = 0; kw < 3; ++kw) { int iw = 2 * ow + kw - 1; if ((unsigned)iw >= 18u) continue;
                    ushort4 v = *(const ushort4*)(in + (size_t)(rb + iw) * 64 + c4 * 4);
                    m.x = v.x > m.x ? v.x : m.x;
                    m.y = v.y > m.y ? v.y : m.y;
                    m.z = v.z > m.z ? v.z : m.z;
                    m.w = v.w > m.w ? v.w : m.w;
                }
            }
        }
    }
    *(ushort4*)(out + (size_t)p * 64 + c4 * 4) = m;
}

// ---------------- MFMA implicit-GEMM residual conv, packed A-tiles ----------------
// TS=1: full 27-tap loop (opt fused epilogue / merged dw). TS=9: tap-split, z = ks*9 + ts.
template <int KC, int FUSE, int TS>
__global__ void convmfma(const ushortT* __restrict__ xb, const ushortT* __restrict__ wt,
                         const float* __restrict__ bias, const ushortT* __restrict__ res,
                         ushortT* __restrict__ outb, float* __restrict__ part,
                         const ushortT* __restrict__ zq,
                         int Ci, int Co, int T, int O, int stride, int chunk,
                         const float* __restrict__ dwW, ushortT* __restrict__ dwOut) {
    if (dwW && blockIdx.y == (unsigned)(Co >> 6)) {
        int O2 = O * O, O3 = O2 * O, O4 = O3 * O;
        int total = Co * O4;
        int sthr = gridDim.x * gridDim.z * 256;
        for (int idx = (blockIdx.z * gridDim.x + blockIdx.x) * 256 + threadIdx.x;
             idx < total; idx += sthr) {
            int co = idx % Co;
            int pos = idx / Co;
            int ow = pos % O, oh = (pos / O) % O, od = (pos / O2) % O, ot = pos / O3;
            int ip = (((2 * ot) * T + 2 * od) * T + 2 * oh) * T + 2 * ow;
            const ushortT* xpp = xb + (size_t)ip * Ci;
            const float* wp = dwW + (size_t)co * Ci;
            float acc = 0.f;
            for (int c8 = 0; c8 < Ci; c8 += 8) {
                uint4 xv = *(const uint4*)(xpp + c8);
                float4 w0 = *(const float4*)(wp + c8);
                float4 w1 = *(const float4*)(wp + c8 + 4);
                acc = fmaf(bf2f((unsigned short)(xv.x & 0xffff)), w0.x, acc);
                acc = fmaf(bf2f((unsigned short)(xv.x >> 16)),    w0.y, acc);
                acc = fmaf(bf2f((unsigned short)(xv.y & 0xffff)), w0.z, acc);
                acc = fmaf(bf2f((unsigned short)(xv.y >> 16)),    w0.w, acc);
                acc = fmaf(bf2f((unsigned short)(xv.z & 0xffff)), w1.x, acc);
                acc = fmaf(bf2f((unsigned short)(xv.z >> 16)),    w1.y, acc);
                acc = fmaf(bf2f((unsigned short)(xv.w & 0xffff)), w1.z, acc);
                acc = fmaf(bf2f((unsigned short)(xv.w >> 16)),    w1.w, acc);
            }
            dwOut[idx] = f2bf(acc);
        }
        return;
    }

    int lane = threadIdx.x & 63;
    int wv = threadIdx.x >> 6;
    int p0 = blockIdx.x * 16;
    int cb = blockIdx.y * 4 + wv;
    int co0 = cb * 16;
    int zz = blockIdx.z;
    int ks, ts;
    if (TS > 1) { ks = zz / TS; ts = zz % TS; } else { ks = zz; ts = 0; }
    int cbase = ks * chunk;
    int kb0 = cbase >> 5;
    size_t nCb = Co >> 4, nKb = Ci >> 5;

    int pn = p0 + (lane & 15);
    int O2 = O * O, O3 = O2 * O, O4 = O3 * O;
    bool pv = pn < O4;
    int pc = pv ? pn : 0;
    int ow = pc % O, oh = (pc / O) % O, od = (pc / O2) % O, ot = pc / O3;
    int g = lane >> 4;
    int kl = cbase + g * 8;

    const ushortT* zp = zq + g * 8;

    f32x4 acc[4];
#pragma unroll
    for (int a = 0; a < 4; ++a) acc[a] = (f32x4){0.f, 0.f, 0.f, 0.f};

    int itb = ot * stride - 1, idb = od * stride - 1, ihb = oh * stride - 1, iwb = ow * stride - 1;

    if (TS == 1) {
#pragma unroll
        for (int i = 0; i < 3; ++i) {
            int it = itb + i;
            bool vt = pv && ((unsigned)it < (unsigned)T);
#pragma unroll
            for (int kd = 0; kd < 3; ++kd) {
                int id = idb + kd;
                bool vdd = vt && ((unsigned)id < (unsigned)T);
                int btd = (it * T + id) * T;
#pragma unroll
                for (int kh = 0; kh < 3; ++kh) {
                    int ih = ihb + kh;
                    bool vh = vdd && ((unsigned)ih < (unsigned)T);
#pragma unroll
                    for (int kw = 0; kw < 3; ++kw) {
                        int iw = iwb + kw;
                        bool v = vh && ((unsigned)iw < (unsigned)T);
                        int ip = (btd + ih) * T + iw;
                        const int tap = (i * 9 + kd * 3 + kh) * 3 + kw;
                        const ushortT* bp = v ? (xb + (size_t)ip * Ci + kl) : zp;
                        const ushortT* ap = wt + (((size_t)tap * nCb + cb) * nKb + kb0) * 512
                                            + lane * 8;
#pragma unroll
                        for (int kc = 0; kc < KC; ++kc) {
                            bf16x8 av = *(const bf16x8*)(ap + kc * 512);
                            bf16x8 bv = *(const bf16x8*)(bp + kc * 32);
                            acc[(tap * KC + kc) & 3] =
                                __builtin_amdgcn_mfma_f32_16x16x32_bf16(av, bv,
                                    acc[(tap * KC + kc) & 3], 0, 0, 0);
                        }
                    }
                }
            }
        }
    } else {
        int i = ts / 3, kd = ts % 3;
        int it = itb + i;
        int id = idb + kd;
        bool vt = pv && ((unsigned)it < (unsigned)T) && ((unsigned)id < (unsigned)T);
        int btd = (it * T + id) * T;
        int tapb = i * 27 + kd * 9;
#pragma unroll
        for (int kh = 0; kh < 3; ++kh) {
            int ih = ihb + kh;
            bool vh = vt && ((unsigned)ih < (unsigned)T);
#pragma unroll
            for (int kw = 0; kw < 3; ++kw) {
                int iw = iwb + kw;
                bool v = vh && ((unsigned)iw < (unsigned)T);
                int ip = (btd + ih) * T + iw;
                int tap = tapb + kh * 3 + kw;
                const ushortT* bp = v ? (xb + (size_t)ip * Ci + kl) : zp;
                const ushortT* ap = wt + (((size_t)tap * nCb + cb) * nKb + kb0) * 512
                                    + lane * 8;
#pragma unroll
                for (int kc = 0; kc < KC; ++kc) {
                    bf16x8 av = *(const bf16x8*)(ap + kc * 512);
                    bf16x8 bv = *(const bf16x8*)(bp + kc * 32);
                    acc[(kh * 3 + kw + kc) & 3] =
                        __builtin_amdgcn_mfma_f32_16x16x32_bf16(av, bv,
                            acc[(kh * 3 + kw + kc) & 3], 0, 0, 0);
                }
            }
        }
    }

    if (!pv) return;
    f32x4 asum;
#pragma unroll
    for (int r = 0; r < 4; ++r)
        asum[r] = (acc[0][r] + acc[1][r]) + (acc[2][r] + acc[3][r]);
    int cob = co0 + g * 4;
    if (FUSE) {
        float bb[4] = {0.f, 0.f, 0.f, 0.f};
        for (int i = 0; i < 3; ++i) {
            int it = itb + i;
            if ((unsigned)it < (unsigned)T) {
#pragma unroll
                for (int rr = 0; rr < 4; ++rr) bb[rr] += bias[i * Co + cob + rr];
            }
        }
        float rv[4] = {0.f, 0.f, 0.f, 0.f};
        if (res) {
            ushort4 r4 = *(const ushort4*)(res + (size_t)pn * Co + cob);
            rv[0] = bf2f(r4.x); rv[1] = bf2f(r4.y); rv[2] = bf2f(r4.z); rv[3] = bf2f(r4.w);
        }
        ushort4 st;
        st.x = f2bf(fmaxf(asum[0] + bb[0] + rv[0], 0.f));
        st.y = f2bf(fmaxf(asum[1] + bb[1] + rv[1], 0.f));
        st.z = f2bf(fmaxf(asum[2] + bb[2] + rv[2], 0.f));
        st.w = f2bf(fmaxf(asum[3] + bb[3] + rv[3], 0.f));
        *(ushort4*)(outb + (size_t)pn * Co + cob) = st;
    } else {
        *(f32x4*)(part + ((size_t)zz * O4 + pn) * Co + cob) = asum;
    }
}

// ---------------- finalize: sum z-slices + T-valid bias + res + relu ----------------
__global__ void finalize_k(const float* __restrict__ part, int KS,
                           const float* __restrict__ bias, const ushortT* __restrict__ res,
                           ushortT* __restrict__ outb, int Co, int O4, int T, int O, int stride,
                           int total) {
    int idx = blockIdx.x * 256 + threadIdx.x;
    if (idx >= total) return;
    int co = idx % Co;
    int pos = idx / Co;
    float v = 0.f;
    for (int z = 0; z < KS; ++z) v += part[((size_t)z * O4 + pos) * Co + co];
    int ot = pos / (O * O * O);
    for (int i = 0; i < 3; ++i) {
        int it = ot * stride + i - 1;
        if ((unsigned)it < (unsigned)T) v += bias[i * Co + co];
    }
    if (res) v += bf2f(res[idx]);
    outb[idx] = f2bf(fmaxf(v, 0.f));
}

// ---------------- avgpool 2^4 + FC (512 -> 1) ----------------
__global__ void avgfc2(const ushortT* __restrict__ xin, const float* __restrict__ fw,
                       const float* __restrict__ fb, float* __restrict__ out) {
    __shared__ float ls[8];
    int t = threadIdx.x; // 512
    float s = 0.f;
#pragma unroll
    for (int pp = 0; pp < 16; ++pp) s += bf2f(xin[pp * 512 + t]);
    s = s * (1.f / 16.f) * fw[t];
    for (int off = 32; off > 0; off >>= 1) s += __shfl_xor(s, off, 64);
    if ((t & 63) == 0) ls[t >> 6] = s;
    __syncthreads();
    if (t == 0) {
        float tot = 0.f;
#pragma unroll
        for (int i = 0; i < 8; ++i) tot += ls[i];
        out[0] = tot + fb[0];
    }
}

extern "C" void kernel_launch(void* const* d_in, const int* in_sizes, int n_in,
                              void* d_out, int out_size, void* d_ws, size_t ws_size,
                              hipStream_t stream) {
    const float* x       = (const float*)d_in[0];
    const float* conv1_w = (const float*)d_in[1];
    const float* l1_w1 = (const float*)d_in[2];
    const float* l1_b1 = (const float*)d_in[3];
    const float* l1_w2 = (const float*)d_in[4];
    const float* l1_b2 = (const float*)d_in[5];
    const float* l2_w1 = (const float*)d_in[6];
    const float* l2_b1 = (const float*)d_in[7];
    const float* l2_w2 = (const float*)d_in[8];
    const float* l2_b2 = (const float*)d_in[9];
    const float* l2_dw = (const float*)d_in[10];
    const float* l3_w1 = (const float*)d_in[11];
    const float* l3_b1 = (const float*)d_in[12];
    const float* l3_w2 = (const float*)d_in[13];
    const float* l3_b2 = (const float*)d_in[14];
    const float* l3_dw = (const float*)d_in[15];
    const float* l4_w1 = (const float*)d_in[16];
    const float* l4_b1 = (const float*)d_in[17];
    const float* l4_w2 = (const float*)d_in[18];
    const float* l4_b2 = (const float*)d_in[19];
    const float* l4_dw = (const float*)d_in[20];
    const float* fc_w  = (const float*)d_in[21];
    const float* fc_b  = (const float*)d_in[22];
    float* outp = (float*)d_out;

    char* bp = (char*)d_ws;
    auto alloc = [&](size_t bytes) {
        char* r = bp;
        bp += (bytes + 255) & ~(size_t)255;
        return (void*)r;
    };
    ushortT* A16 = (ushortT*)alloc(6718464ull * 2); // conv1 out bf16 [18^4][64]
    ushortT* XP  = (ushortT*)alloc(3556224ull * 2); // padded bf16 x [42][42][42][48]
    ushortT* Aw1 = (ushortT*)alloc(200704ull * 2);
    ushortT* X0 = (ushortT*)alloc(419904ull * 2);
    ushortT* Y1 = (ushortT*)alloc(419904ull * 2);
    ushortT* X1 = (ushortT*)alloc(419904ull * 2);
    ushortT* Y2 = (ushortT*)alloc(80000ull * 2);
    ushortT* R2 = (ushortT*)alloc(80000ull * 2);
    ushortT* X2 = (ushortT*)alloc(80000ull * 2);
    ushortT* Y3 = (ushortT*)alloc(20736ull * 2);
    ushortT* R3 = (ushortT*)alloc(20736ull * 2);
    ushortT* X3 = (ushortT*)alloc(20736ull * 2);
    ushortT* Y4 = (ushortT*)alloc(8192ull * 2);
    ushortT* R4 = (ushortT*)alloc(8192ull * 2);
    ushortT* X4 = (ushortT*)alloc(8192ull * 2);
    ushortT* W11 = (ushortT*)alloc(331776ull * 2);
    ushortT* W12 = (ushortT*)alloc(331776ull * 2);
    ushortT* W21 = (ushortT*)alloc(663552ull * 2);
    ushortT* W22 = (ushortT*)alloc(1327104ull * 2);
    ushortT* W31 = (ushortT*)alloc(2654208ull * 2);
    ushortT* W32 = (ushortT*)alloc(5308416ull * 2);
    ushortT* W41 = (ushortT*)alloc(10616832ull * 2);
    ushortT* W42 = (ushortT*)alloc(21233664ull * 2);
    float* P    = (float*)alloc(1492992ull * 4);   // max: l3c2 72 x 81 x 256
    ushortT* ZB = (ushortT*)alloc(256);
    if ((size_t)(bp - (char*)d_ws) > ws_size) return; // workspace too small: fail cleanly

    // 1) pad/convert x + conv1 weights + packed residual weight prep
    prep0<<<5593, 256, 0, stream>>>(x, conv1_w,
                                    l1_w1, l1_w2, l2_w1, l2_w2, l3_w1, l3_w2, l4_w1, l4_w2,
                                    XP, Aw1,
                                    W11, W12, W21, W22, W31, W32, W41, W42);

    // 2) conv1 MFMA (stride-26 LDS + XCD swizzle; r17 2x6 wave split)
    mega_kernel<<<1350, 128, 0, stream>>>(XP, Aw1, A16);

    // 3) stem pool (+ zero ZB)
    maxpool2<<<411, 256, 0, stream>>>(A16, X0, ZB);

    // 4) layer1
    convmfma<2, 1, 1><<<dim3(411, 1, 1), 256, 0, stream>>>(
        X0, W11, l1_b1, nullptr, Y1, nullptr, ZB, 64, 64, 9, 9, 1, 64, nullptr, nullptr);
    convmfma<2, 1, 1><<<dim3(411, 1, 1), 256, 0, stream>>>(
        Y1, W12, l1_b2, X0, X1, nullptr, ZB, 64, 64, 9, 9, 1, 64, nullptr, nullptr);

    // 5) layer2 (dw merged into c1)
    convmfma<2, 1, 1><<<dim3(40, 3, 1), 256, 0, stream>>>(
        X1, W21, l2_b1, nullptr, Y2, nullptr, ZB, 64, 128, 9, 5, 2, 64, l2_dw, R2);
    convmfma<4, 1, 1><<<dim3(40, 2, 1), 256, 0, stream>>>(
        Y2, W22, l2_b2, R2, X2, nullptr, ZB, 128, 128, 5, 5, 1, 128, nullptr, nullptr);

    // 6) layer3: c1 KS=4 x TS=9 (+dw); c2 KS=8 x TS=9
    convmfma<1, 0, 9><<<dim3(6, 5, 36), 256, 0, stream>>>(
        X2, W31, nullptr, nullptr, nullptr, P, ZB, 128, 256, 5, 3, 2, 32, l3_dw, R3);
    finalize_k<<<81, 256, 0, stream>>>(P, 36, l3_b1, nullptr, Y3, 256, 81, 5, 3, 2, 20736);
    convmfma<1, 0, 9><<<dim3(6, 4, 72), 256, 0, stream>>>(
        Y3, W32, nullptr, nullptr, nullptr, P, ZB, 256, 256, 3, 3, 1, 32, nullptr, nullptr);
    finalize_k<<<81, 256, 0, stream>>>(P, 72, l3_b2, R3, X3, 256, 81, 3, 3, 1, 20736);

    // 7) layer4: c1 KS=8 x TS=9 (+dw); c2 KS=16 x TS=9
    convmfma<1, 0, 9><<<dim3(1, 9, 72), 256, 0, stream>>>(
        X3, W41, nullptr, nullptr, nullptr, P, ZB, 256, 512, 3, 2, 2, 32, l4_dw, R4);
    finalize_k<<<32, 256, 0, stream>>>(P, 72, l4_b1, nullptr, Y4, 512, 16, 3, 2, 2, 8192);
    convmfma<1, 0, 9><<<dim3(1, 8, 144), 256, 0, stream>>>(
        Y4, W42, nullptr, nullptr, nullptr, P, ZB, 512, 512, 2, 2, 1, 32, nullptr, nullptr);
    finalize_k<<<32, 256, 0, stream>>>(P, 144, l4_b2, R4, X4, 512, 16, 2, 2, 1, 8192);

    // 8) head
    avgfc2<<<1, 512, 0, stream>>>(X4, fc_w, fc_b, outp);
}